// Round 18
// baseline (507.953 us; speedup 1.0000x reference)
//
#include <hip/hip_runtime.h>
#include <hip/hip_bf16.h>
#include <stdint.h>

// Problem constants (match setup_inputs)
#define M_ROWS 100352   // 2048 * 49
#define C_DIM  512
#define QKV_N  1536
#define NH     16
#define HD     32
#define NWIN   49       // window tokens (7*7)
#define NMASK  64

typedef __attribute__((ext_vector_type(4))) float        f32x4;
typedef __attribute__((ext_vector_type(8))) short        bf16x8;
typedef __attribute__((ext_vector_type(4))) unsigned int u32x4;

static __device__ __forceinline__ unsigned short f32_to_bf16(float f) {
  union { float f; unsigned int u; } v; v.f = f;
  unsigned int u = v.u;
  return (unsigned short)((u + 0x7FFFu + ((u >> 16) & 1u)) >> 16);  // RNE
}

// global -> LDS direct DMA, 16B per lane. dest = wave-uniform base + lane*16.
static __device__ __forceinline__ void gload_lds16(const void* g, void* l) {
  __builtin_amdgcn_global_load_lds(
      (const __attribute__((address_space(1))) unsigned int*)g,
      (__attribute__((address_space(3))) unsigned int*)l, 16, 0, 0);
}

// ---------------------------------------------------------------- k_cvt
__global__ void k_cvt(const float* __restrict__ in, unsigned short* __restrict__ out, int n4) {
  int i = blockIdx.x * blockDim.x + threadIdx.x;
  int stride = gridDim.x * blockDim.x;
  for (; i < n4; i += stride) {
    float4 v = ((const float4*)in)[i];
    ushort4 o = make_ushort4(f32_to_bf16(v.x), f32_to_bf16(v.y),
                             f32_to_bf16(v.z), f32_to_bf16(v.w));
    ((ushort4*)out)[i] = o;
  }
}

// ------------------------------------------- transpose + convert weights
// in: K x N f32 (row-major), out: N x K bf16 (row-major) == B^T
__global__ void k_transpose_cvt(const float* __restrict__ in, unsigned short* __restrict__ out,
                                int K, int N) {
  __shared__ float t[32][33];
  const int n0 = blockIdx.x * 32, k0 = blockIdx.y * 32;
  const int tx = threadIdx.x & 31, ty = threadIdx.x >> 5;  // 32 x 8
#pragma unroll
  for (int rr = 0; rr < 32; rr += 8)
    t[ty + rr][tx] = in[(size_t)(k0 + ty + rr) * N + n0 + tx];
  __syncthreads();
#pragma unroll
  for (int rr = 0; rr < 32; rr += 8)
    out[(size_t)(n0 + ty + rr) * K + k0 + tx] = f32_to_bf16(t[tx][ty + rr]);
}

// ----------------------------------------- fused bias+mask table (padded)
__global__ __launch_bounds__(256) void k_bm(const float* __restrict__ mask,
                                            const float* __restrict__ rel,
                                            float* __restrict__ bmt) {
  const int idx = blockIdx.x * 256 + threadIdx.x;   // w<<16 | h<<12 | i<<6 | j
  const int j = idx & 63, i = (idx >> 6) & 63, h = (idx >> 12) & 15, w = idx >> 16;
  float v = -1e30f;
  if (i < NWIN && j < NWIN) {
    const int rpi = ((j / 7) - (i / 7) + 6) * 13;
    v = mask[w * (NWIN * NWIN) + i * NWIN + j] + rel[rpi * NH + h];
  }
  bmt[idx] = v;
}

#define WAITB(N)                                              \
  do {                                                        \
    asm volatile("s_waitcnt vmcnt(" #N ")" ::: "memory");     \
    __builtin_amdgcn_sched_barrier(0);                        \
    __builtin_amdgcn_s_barrier();                             \
    __builtin_amdgcn_sched_barrier(0);                        \
  } while (0)

// ------------------------------------------------------------------ GEMM
// EXACT r5/r12 4-phase 256x256 K-loop (schedule-fragile; never touched).
// OUT_MODE: 0 = f32 row-major, 1 = bf16 row-major,
//           2 = bf16 qkv-blocked [b][h][{q,k,v}][49][32] (attn-friendly).
template <int OUT_MODE>
static __device__ __forceinline__ void gemm256_body(const unsigned short* __restrict__ A,
                                                    const unsigned short* __restrict__ BT,
                                                    const float* __restrict__ bias,
                                                    void* __restrict__ Cout,
                                                    int M, int N, int K,
                                                    unsigned short* lds0) {
  unsigned short (*lds)[2][16384] = (unsigned short (*)[2][16384])lds0;
  const int tid = threadIdx.x;
  const int lane = tid & 63, wave = tid >> 6;
  const int wr = wave >> 2, wc = wave & 3;      // 2 x 4 wave grid
  const int lr = lane & 15, lg = lane >> 4;

  // bijective XCD swizzle (gridDim.x % 8 == 0 for all call sites)
  const int nwg = gridDim.x, q8 = nwg >> 3;
  const int wg = (blockIdx.x & 7) * q8 + (blockIdx.x >> 3);
  const int gx = N >> 8;
  const int bx = wg % gx, by = wg / gx;
  const int m0 = by << 8, n0 = bx << 8;

  const int srow = lane & 15;
  const int scol = (lane >> 4) * 8;
  const int sRG = wave >> 1;
  const int scg = wave & 1;

  const f32x4 fz = {0.f, 0.f, 0.f, 0.f};
  f32x4 acc[8][4];
#pragma unroll
  for (int i = 0; i < 8; ++i)
#pragma unroll
    for (int j = 0; j < 4; ++j) acc[i][j] = fz;

  const int NT = K >> 6;

  auto stageU = [&](const unsigned short* G, int gbase, int op, int t, int u) {
    const int RG = 4 * u + sRG;  // row-group 0..15
    gload_lds16(G + (size_t)(gbase + RG * 16 + srow) * K + (t << 6) + scg * 32 + scol,
                &lds[t & 1][op][(RG >> 3) * 8192 + (((RG & 7) << 1) + scg) * 512]);
  };

  const int roff = lg * 128 + lr * 8;

  bf16x8 af[4][2];
  bf16x8 bf[2][2];
  bf16x8 bg[2][2];

#define LDA(h, mh)                                                              \
  do {                                                                          \
    const unsigned short* la = &lds[(h) & 1][0][wr * 8192];                     \
    _Pragma("unroll") for (int m = 0; m < 4; ++m)                               \
    _Pragma("unroll") for (int ks = 0; ks < 2; ++ks)                            \
        af[m][ks] = *(const bf16x8*)(la + ((((mh)*4 + m) * 2 + ks) * 512) + roff); \
  } while (0)

#define LDB(h, nh, DST)                                                         \
  do {                                                                          \
    const unsigned short* lb = &lds[(h) & 1][1][(wc >> 1) * 8192];              \
    _Pragma("unroll") for (int n = 0; n < 2; ++n)                               \
    _Pragma("unroll") for (int ks = 0; ks < 2; ++ks)                            \
        DST[n][ks] = *(const bf16x8*)(lb + ((((wc & 1) * 4 + (nh)*2 + n) * 2 + ks) * 512) + roff); \
  } while (0)

#define MFMA16(mh, nh, B)                                                       \
  do {                                                                          \
    __builtin_amdgcn_s_setprio(1);                                              \
    _Pragma("unroll") for (int m = 0; m < 4; ++m)                               \
    _Pragma("unroll") for (int n = 0; n < 2; ++n)                               \
    _Pragma("unroll") for (int ks = 0; ks < 2; ++ks)                            \
        acc[(mh)*4 + m][(nh)*2 + n] = __builtin_amdgcn_mfma_f32_16x16x32_bf16(  \
            af[m][ks], B[n][ks], acc[(mh)*4 + m][(nh)*2 + n], 0, 0, 0);         \
    __builtin_amdgcn_s_setprio(0);                                              \
  } while (0)

  // prologue: tile 0, unit order B0 B1 B2 B3 A0 A2 A1 A3 (8 loads/lane)
  stageU(BT, n0, 1, 0, 0); stageU(BT, n0, 1, 0, 1);
  stageU(BT, n0, 1, 0, 2); stageU(BT, n0, 1, 0, 3);
  stageU(A,  m0, 0, 0, 0); stageU(A,  m0, 0, 0, 2);
  stageU(A,  m0, 0, 0, 1); stageU(A,  m0, 0, 0, 3);

  for (int h = 0; h < NT - 1; ++h) {
    const int t1 = h + 1;
    WAITB(2);
    stageU(BT, n0, 1, t1, 0); stageU(BT, n0, 1, t1, 1);
    LDA(h, 0);
    LDB(h, 0, bf);
    MFMA16(0, 0, bf);
    stageU(BT, n0, 1, t1, 2); stageU(BT, n0, 1, t1, 3);
    LDB(h, 1, bg);
    MFMA16(0, 1, bg);
    WAITB(4);
    stageU(A, m0, 0, t1, 0); stageU(A, m0, 0, t1, 2);
    LDA(h, 1);
    MFMA16(1, 1, bg);
    stageU(A, m0, 0, t1, 1); stageU(A, m0, 0, t1, 3);
    LDB(h, 0, bf);
    MFMA16(1, 0, bf);
  }
  {  // last tile, peeled
    const int h = NT - 1;
    WAITB(2);
    LDA(h, 0);
    LDB(h, 0, bf);
    MFMA16(0, 0, bf);
    LDB(h, 1, bg);
    MFMA16(0, 1, bg);
    WAITB(0);
    LDA(h, 1);
    MFMA16(1, 1, bg);
    LDB(h, 0, bf);
    MFMA16(1, 0, bf);
  }
#undef LDA
#undef LDB
#undef MFMA16

  float bv[4];
#pragma unroll
  for (int nj = 0; nj < 4; ++nj) bv[nj] = bias[n0 + wc * 64 + nj * 16 + lr];
#pragma unroll
  for (int mi = 0; mi < 8; ++mi)
#pragma unroll
    for (int nj = 0; nj < 4; ++nj)
#pragma unroll
      for (int r = 0; r < 4; ++r) {
        const int row = m0 + wr * 128 + mi * 16 + 4 * lg + r;
        const int col = n0 + wc * 64 + nj * 16 + lr;
        const float v = acc[mi][nj][r] + bv[nj];
        if (OUT_MODE == 2) {
          // qkv-blocked: row -> (b = row/49, i = row%49); col -> (which, h, d)
          const unsigned int b = (unsigned int)row / 49u;
          const unsigned int i = (unsigned int)row - b * 49u;
          const int which = col >> 9, hh = (col >> 5) & 15, d = col & 31;
          ((unsigned short*)Cout)[(((size_t)b * NH + hh) * 147 + which * 49 + i) * 32 + d] =
              f32_to_bf16(v);
        } else if (OUT_MODE == 1) {
          ((unsigned short*)Cout)[(size_t)row * N + col] = f32_to_bf16(v);
        } else {
          ((float*)Cout)[(size_t)row * N + col] = v;
        }
      }
}

__global__ __launch_bounds__(512, 2) void k_gemm_qkv(const unsigned short* __restrict__ A,
                                                     const unsigned short* __restrict__ BT,
                                                     const float* __restrict__ bias,
                                                     void* __restrict__ Cout,
                                                     int M, int N, int K) {
  __shared__ __align__(16) unsigned short lds[2][2][16384];  // 128 KB
  gemm256_body<2>(A, BT, bias, Cout, M, N, K, &lds[0][0][0]);
}

__global__ __launch_bounds__(512, 2) void k_gemm_proj(const unsigned short* __restrict__ A,
                                                      const unsigned short* __restrict__ BT,
                                                      const float* __restrict__ bias,
                                                      void* __restrict__ Cout,
                                                      int M, int N, int K) {
  __shared__ __align__(16) unsigned short lds[2][2][16384];  // 128 KB
  gemm256_body<0>(A, BT, bias, Cout, M, N, K, &lds[0][0][0]);
}

// ------------------------------------------------------------- attention
// ILP variant: each wave processes TWO windows b0, b1 = b0+64 sharing the
// same (w,h) -> same bml table.  Pair-1's global loads (q/k frags; V into
// HELD REGISTERS, T14 issue-early/write-late) are issued before pair-0's
// compute, so pair-0's QK^T+softmax+PV (~2000+ cyc) hides pair-1's HBM
// latency; pair-0 completes fully (incl. store) before pair-1's scores
// materialize (caps VGPR).  Block = (w,h,tg): 4 waves x 2 pairs, grid 4096.
// LDS: bml 16.9K + PV[8][2112] merged P/V per pair (r15-proven) = 50.7 KB
// -> 3 blocks/CU.  r15 showed TLP is not binding, so the occupancy trade
// (VGPR ~180 -> ~8 waves/CU) is acceptable if the chain hypothesis holds.
__global__ __launch_bounds__(256) void k_attn(const unsigned short* __restrict__ qkv,
                                              const float* __restrict__ bmt,
                                              unsigned short* __restrict__ aout) {
  const int wave = threadIdx.x >> 6, lane = threadIdx.x & 63;
  const int lr = lane & 15, lg = lane >> 4;

  // bijective XCD swizzle over 4096 blocks (q8 = 512): XCD x gets w in [8x,8x+8)
  const int s = (blockIdx.x & 7) * 512 + (blockIdx.x >> 3);
  const int w = s >> 6, h = (s >> 2) & 15, tg = s & 3;
  const int b0 = w + 64 * (tg * 8 + wave * 2);
  const int b1 = b0 + 64;

  __shared__ float bml[64 * 66];                        // 16.9 KB shared table
  __shared__ __align__(16) unsigned short PV[8][2112];  // per-pair V^T, then P
  unsigned short* vt0 = PV[wave * 2 + 0];
  unsigned short* pl0 = PV[wave * 2 + 0];
  unsigned short* vt1 = PV[wave * 2 + 1];
  unsigned short* pl1 = PV[wave * 2 + 1];

  // ---- stage bmt(w,h) -> LDS (coalesced 16 KB read; issued first) ----
  const float* tbl = bmt + ((size_t)(w * NH + h) << 12);
#pragma unroll
  for (int it = 0; it < 4; ++it) {
    const int c = threadIdx.x + 256 * it;   // 16B chunk 0..1023
    const int row = c >> 4, col4 = c & 15;
    const f32x4 t4 = *(const f32x4*)(tbl + row * 64 + col4 * 4);
    float* dst = &bml[row * 66 + col4 * 4];
    dst[0] = t4[0]; dst[1] = t4[1]; dst[2] = t4[2]; dst[3] = t4[3];
  }

  const unsigned short* qp0 = qkv + ((size_t)(b0 * NH + h) * 147) * 32;
  const unsigned short* kp0 = qp0 + 49 * 32;
  const unsigned short* vp0 = qp0 + 2 * 49 * 32;
  const unsigned short* qp1 = qkv + ((size_t)(b1 * NH + h) * 147) * 32;
  const unsigned short* kp1 = qp1 + 49 * 32;
  const unsigned short* vp1 = qp1 + 2 * 49 * 32;

  // pair-0 q/k frags
  bf16x8 kf0[4], qf0[4];
#pragma unroll
  for (int t = 0; t < 4; ++t) {
    kf0[t] = *(const bf16x8*)(kp0 + (t * 16 + lr) * 32 + lg * 8);
    qf0[t] = *(const bf16x8*)(qp0 + (t * 16 + lr) * 32 + lg * 8);
  }
  // pair-1 q/k frags issued EARLY (latency hidden under pair-0 compute)
  bf16x8 kf1[4], qf1[4];
#pragma unroll
  for (int t = 0; t < 4; ++t) {
    kf1[t] = *(const bf16x8*)(kp1 + (t * 16 + lr) * 32 + lg * 8);
    qf1[t] = *(const bf16x8*)(qp1 + (t * 16 + lr) * 32 + lg * 8);
  }

  const u32x4 zv = {0u, 0u, 0u, 0u};
  // V0: read + write to LDS now
#pragma unroll
  for (int c0 = 0; c0 < 4; ++c0) {
    const int c = c0 * 64 + lane;
    const int key = c >> 2, d0 = (c & 3) << 3;
    union { u32x4 v; unsigned short ss[8]; } tmp;
    tmp.v = (key < NWIN) ? *(const u32x4*)(vp0 + key * 32 + d0) : zv;
#pragma unroll
    for (int jj = 0; jj < 8; ++jj) vt0[(d0 + jj) * 66 + key] = tmp.ss[jj];
  }
  // V1: global reads issued NOW into held registers; LDS write deferred
  u32x4 v1r0, v1r1, v1r2, v1r3;
  {
    const int key0 = lane >> 2, d00 = (lane & 3) << 3;
    v1r0 = (key0 < NWIN) ? *(const u32x4*)(vp1 + key0 * 32 + d00) : zv;
    const int c1 = 64 + lane, key1 = c1 >> 2, d01 = (c1 & 3) << 3;
    v1r1 = (key1 < NWIN) ? *(const u32x4*)(vp1 + key1 * 32 + d01) : zv;
    const int c2 = 128 + lane, key2 = c2 >> 2, d02 = (c2 & 3) << 3;
    v1r2 = (key2 < NWIN) ? *(const u32x4*)(vp1 + key2 * 32 + d02) : zv;
    const int c3 = 192 + lane, key3 = c3 >> 2, d03 = (c3 & 3) << 3;
    v1r3 = (key3 < NWIN) ? *(const u32x4*)(vp1 + key3 * 32 + d03) : zv;
  }

  const f32x4 fz = {0.f, 0.f, 0.f, 0.f};
  const float scale = 0.1767766952966369f;

  union VU { unsigned int u[4]; bf16x8 v; };

  // ---------------- pair 0: QK^T ----------------
  f32x4 s4[4][4];
#pragma unroll
  for (int mi = 0; mi < 4; ++mi)
#pragma unroll
    for (int ni = 0; ni < 4; ++ni) s4[mi][ni] = fz;
#pragma unroll
  for (int mi = 0; mi < 4; ++mi)
#pragma unroll
    for (int ni = 0; ni < 4; ++ni)
      s4[mi][ni] = __builtin_amdgcn_mfma_f32_16x16x32_bf16(kf0[mi], qf0[ni], s4[mi][ni], 0, 0, 0);

  VU vfr[2][2];
#pragma unroll
  for (int nj = 0; nj < 2; ++nj)
#pragma unroll
    for (int ks = 0; ks < 2; ++ks) {
      const int base = ((16 * nj + lr) * 66 + 32 * ks + 8 * lg) >> 1;
#pragma unroll
      for (int u = 0; u < 4; ++u) vfr[nj][ks].u[u] = ((const unsigned int*)vt0)[base + u];
    }

  __syncthreads();  // bml staged by all waves (V/P regions are wave-private)

  // ---------------- pair 0: softmax + PV + store ----------------
  {
    f32x4 o[4][2];
#pragma unroll
    for (int qi = 0; qi < 4; ++qi)
#pragma unroll
      for (int nj = 0; nj < 2; ++nj) o[qi][nj] = fz;

#pragma unroll
    for (int ni = 0; ni < 4; ++ni) {
      float v[16];
      float mx = -3e38f;
      const float* brow = &bml[(16 * ni + lr) * 66];
#pragma unroll
      for (int mi = 0; mi < 4; ++mi) {
#pragma unroll
        for (int r = 0; r < 4; ++r) {
          v[mi * 4 + r] = fmaf(s4[mi][ni][r], scale, brow[16 * mi + 4 * lg + r]);
          mx = fmaxf(mx, v[mi * 4 + r]);
        }
      }
      mx = fmaxf(mx, __shfl_xor(mx, 16));
      mx = fmaxf(mx, __shfl_xor(mx, 32));
      float sum = 0.f;
#pragma unroll
      for (int t = 0; t < 16; ++t) {
        v[t] = __expf(v[t] - mx);
        sum += v[t];
      }
      sum += __shfl_xor(sum, 16);
      sum += __shfl_xor(sum, 32);
      const float inv = __builtin_amdgcn_rcpf(sum);

      const int ip = 16 * (ni & 1) + lr;
#pragma unroll
      for (int mi = 0; mi < 4; ++mi) {
        const unsigned int lo = (unsigned int)f32_to_bf16(v[mi * 4 + 0] * inv) |
                                ((unsigned int)f32_to_bf16(v[mi * 4 + 1] * inv) << 16);
        const unsigned int hi = (unsigned int)f32_to_bf16(v[mi * 4 + 2] * inv) |
                                ((unsigned int)f32_to_bf16(v[mi * 4 + 3] * inv) << 16);
        const int byteoff = 32 * mi + 8 * lg;
        const int sw = byteoff ^ ((ip & 7) << 4);
        uint2 w2; w2.x = lo; w2.y = hi;
        *(uint2*)((char*)pl0 + ip * 128 + sw) = w2;
      }

      if (ni & 1) {
        asm volatile("s_waitcnt lgkmcnt(0)" ::: "memory");
        __builtin_amdgcn_sched_barrier(0);
        const int half = ni >> 1;
#pragma unroll
        for (int q2 = 0; q2 < 2; ++q2) {
          const int qi = half * 2 + q2;
          const int ipr = 16 * q2 + lr;
#pragma unroll
          for (int ks = 0; ks < 2; ++ks) {
            const int bo = 64 * ks + 16 * lg;
            const int swr = bo ^ ((ipr & 7) << 4);
            const bf16x8 pa = *(const bf16x8*)((const char*)pl0 + ipr * 128 + swr);
#pragma unroll
            for (int nj = 0; nj < 2; ++nj)
              o[qi][nj] = __builtin_amdgcn_mfma_f32_16x16x32_bf16(pa, vfr[nj][ks].v, o[qi][nj], 0, 0, 0);
          }
        }
      }
    }

    const size_t orow = (size_t)b0 * NWIN;
#pragma unroll
    for (int qi = 0; qi < 4; ++qi)
#pragma unroll
      for (int r = 0; r < 4; ++r) {
        const int i = 16 * qi + 4 * lg + r;
        if (i < NWIN) {
#pragma unroll
          for (int nj = 0; nj < 2; ++nj)
            aout[(orow + i) * C_DIM + h * HD + 16 * nj + lr] = f32_to_bf16(o[qi][nj][r]);
        }
      }
  }

  // ---------------- pair 1: write V, QK^T, softmax + PV + store ----------------
  {
    const int key0 = lane >> 2, d00 = (lane & 3) << 3;
    union { u32x4 v; unsigned short ss[8]; } t0; t0.v = v1r0;
#pragma unroll
    for (int jj = 0; jj < 8; ++jj) vt1[(d00 + jj) * 66 + key0] = t0.ss[jj];
    const int c1 = 64 + lane, key1 = c1 >> 2, d01 = (c1 & 3) << 3;
    union { u32x4 v; unsigned short ss[8]; } t1; t1.v = v1r1;
#pragma unroll
    for (int jj = 0; jj < 8; ++jj) vt1[(d01 + jj) * 66 + key1] = t1.ss[jj];
    const int c2 = 128 + lane, key2 = c2 >> 2, d02 = (c2 & 3) << 3;
    union { u32x4 v; unsigned short ss[8]; } t2; t2.v = v1r2;
#pragma unroll
    for (int jj = 0; jj < 8; ++jj) vt1[(d02 + jj) * 66 + key2] = t2.ss[jj];
    const int c3 = 192 + lane, key3 = c3 >> 2, d03 = (c3 & 3) << 3;
    union { u32x4 v; unsigned short ss[8]; } t3; t3.v = v1r3;
#pragma unroll
    for (int jj = 0; jj < 8; ++jj) vt1[(d03 + jj) * 66 + key3] = t3.ss[jj];
  }

  f32x4 s5[4][4];
#pragma unroll
  for (int mi = 0; mi < 4; ++mi)
#pragma unroll
    for (int ni = 0; ni < 4; ++ni) s5[mi][ni] = fz;
#pragma unroll
  for (int mi = 0; mi < 4; ++mi)
#pragma unroll
    for (int ni = 0; ni < 4; ++ni)
      s5[mi][ni] = __builtin_amdgcn_mfma_f32_16x16x32_bf16(kf1[mi], qf1[ni], s5[mi][ni], 0, 0, 0);

  VU vfr1[2][2];
#pragma unroll
  for (int nj = 0; nj < 2; ++nj)
#pragma unroll
    for (int ks = 0; ks < 2; ++ks) {
      const int base = ((16 * nj + lr) * 66 + 32 * ks + 8 * lg) >> 1;
#pragma unroll
      for (int u = 0; u < 4; ++u) vfr1[nj][ks].u[u] = ((const unsigned int*)vt1)[base + u];
    }

  {
    f32x4 o[4][2];
#pragma unroll
    for (int qi = 0; qi < 4; ++qi)
#pragma unroll
      for (int nj = 0; nj < 2; ++nj) o[qi][nj] = fz;

#pragma unroll
    for (int ni = 0; ni < 4; ++ni) {
      float v[16];
      float mx = -3e38f;
      const float* brow = &bml[(16 * ni + lr) * 66];
#pragma unroll
      for (int mi = 0; mi < 4; ++mi) {
#pragma unroll
        for (int r = 0; r < 4; ++r) {
          v[mi * 4 + r] = fmaf(s5[mi][ni][r], scale, brow[16 * mi + 4 * lg + r]);
          mx = fmaxf(mx, v[mi * 4 + r]);
        }
      }
      mx = fmaxf(mx, __shfl_xor(mx, 16));
      mx = fmaxf(mx, __shfl_xor(mx, 32));
      float sum = 0.f;
#pragma unroll
      for (int t = 0; t < 16; ++t) {
        v[t] = __expf(v[t] - mx);
        sum += v[t];
      }
      sum += __shfl_xor(sum, 16);
      sum += __shfl_xor(sum, 32);
      const float inv = __builtin_amdgcn_rcpf(sum);

      const int ip = 16 * (ni & 1) + lr;
#pragma unroll
      for (int mi = 0; mi < 4; ++mi) {
        const unsigned int lo = (unsigned int)f32_to_bf16(v[mi * 4 + 0] * inv) |
                                ((unsigned int)f32_to_bf16(v[mi * 4 + 1] * inv) << 16);
        const unsigned int hi = (unsigned int)f32_to_bf16(v[mi * 4 + 2] * inv) |
                                ((unsigned int)f32_to_bf16(v[mi * 4 + 3] * inv) << 16);
        const int byteoff = 32 * mi + 8 * lg;
        const int sw = byteoff ^ ((ip & 7) << 4);
        uint2 w2; w2.x = lo; w2.y = hi;
        *(uint2*)((char*)pl1 + ip * 128 + sw) = w2;
      }

      if (ni & 1) {
        asm volatile("s_waitcnt lgkmcnt(0)" ::: "memory");
        __builtin_amdgcn_sched_barrier(0);
        const int half = ni >> 1;
#pragma unroll
        for (int q2 = 0; q2 < 2; ++q2) {
          const int qi = half * 2 + q2;
          const int ipr = 16 * q2 + lr;
#pragma unroll
          for (int ks = 0; ks < 2; ++ks) {
            const int bo = 64 * ks + 16 * lg;
            const int swr = bo ^ ((ipr & 7) << 4);
            const bf16x8 pa = *(const bf16x8*)((const char*)pl1 + ipr * 128 + swr);
#pragma unroll
            for (int nj = 0; nj < 2; ++nj)
              o[qi][nj] = __builtin_amdgcn_mfma_f32_16x16x32_bf16(pa, vfr1[nj][ks].v, o[qi][nj], 0, 0, 0);
          }
        }
      }
    }

    const size_t orow = (size_t)b1 * NWIN;
#pragma unroll
    for (int qi = 0; qi < 4; ++qi)
#pragma unroll
      for (int r = 0; r < 4; ++r) {
        const int i = 16 * qi + 4 * lg + r;
        if (i < NWIN) {
#pragma unroll
          for (int nj = 0; nj < 2; ++nj)
            aout[(orow + i) * C_DIM + h * HD + 16 * nj + lr] = f32_to_bf16(o[qi][nj][r]);
        }
      }
  }
}

// ---------------------------------------------------------------- launch
static const size_t SZ_QKV = (size_t)M_ROWS * QKV_N * 2;   // 308 MB (blocked layout)
static const size_t SZ_XB  = (size_t)M_ROWS * C_DIM * 2;
static const size_t SZ_WQ  = (size_t)QKV_N * C_DIM * 2;
static const size_t OFF_QKV = 0;
static const size_t OFF_XB  = OFF_QKV + SZ_QKV;   // x_bf16, later attn_out
static const size_t OFF_WQ  = OFF_XB + SZ_XB;
static const size_t OFF_WP  = OFF_WQ + SZ_WQ;

extern "C" void kernel_launch(void* const* d_in, const int* in_sizes, int n_in,
                              void* d_out, int out_size, void* d_ws, size_t ws_size,
                              hipStream_t stream) {
  const float* x      = (const float*)d_in[0];
  const float* mask   = (const float*)d_in[1];
  const float* qkv_w  = (const float*)d_in[2];
  const float* qkv_b  = (const float*)d_in[3];
  const float* proj_w = (const float*)d_in[4];
  const float* proj_b = (const float*)d_in[5];
  const float* rel    = (const float*)d_in[6];
  float* out = (float*)d_out;

  char* ws = (char*)d_ws;
  unsigned short* qkvb = (unsigned short*)(ws + OFF_QKV);
  unsigned short* xb   = (unsigned short*)(ws + OFF_XB);
  unsigned short* wqT  = (unsigned short*)(ws + OFF_WQ);
  unsigned short* wpT  = (unsigned short*)(ws + OFF_WP);
  // bmt (16.78 MB) in d_out scratch: fully consumed by k_attn before final GEMM.
  float* bmt = (float*)d_out;

  k_cvt<<<2048, 256, 0, stream>>>(x, xb, M_ROWS * C_DIM / 4);
  k_transpose_cvt<<<dim3(QKV_N / 32, C_DIM / 32), 256, 0, stream>>>(qkv_w, wqT, C_DIM, QKV_N);
  k_transpose_cvt<<<dim3(C_DIM / 32, C_DIM / 32), 256, 0, stream>>>(proj_w, wpT, C_DIM, C_DIM);
  k_bm<<<(NMASK * NH * 64 * 64) / 256, 256, 0, stream>>>(mask, rel, bmt);

  // qkv = x @ qkv_w + qkv_b  (bf16, blocked layout), grid 6*392 = 2352 (%8==0)
  k_gemm_qkv<<<(QKV_N / 256) * (M_ROWS / 256), 512, 0, stream>>>(
      xb, wqT, qkv_b, qkvb, M_ROWS, QKV_N, C_DIM);

  // attention -> attn_out (reuses xb region), 4096 blocks (%8==0), 2 b's/wave
  k_attn<<<NMASK * NH * 4, 256, 0, stream>>>(qkvb, bmt, xb);

  // out = attn_out @ proj_w + proj_b  (f32 out), grid 2*392 = 784 (%8==0)
  k_gemm_proj<<<(C_DIM / 256) * (M_ROWS / 256), 512, 0, stream>>>(
      xb, wpT, proj_b, out, M_ROWS, C_DIM, C_DIM);
}

// Round 19
// 495.034 us; speedup vs baseline: 1.0261x; 1.0261x over previous
//
#include <hip/hip_runtime.h>
#include <hip/hip_bf16.h>
#include <stdint.h>

// Problem constants (match setup_inputs)
#define M_ROWS 100352   // 2048 * 49
#define C_DIM  512
#define QKV_N  1536
#define NH     16
#define HD     32
#define NWIN   49       // window tokens (7*7)
#define NMASK  64

typedef __attribute__((ext_vector_type(4))) float        f32x4;
typedef __attribute__((ext_vector_type(8))) short        bf16x8;
typedef __attribute__((ext_vector_type(4))) unsigned int u32x4;

static __device__ __forceinline__ unsigned short f32_to_bf16(float f) {
  union { float f; unsigned int u; } v; v.f = f;
  unsigned int u = v.u;
  return (unsigned short)((u + 0x7FFFu + ((u >> 16) & 1u)) >> 16);  // RNE
}

// global -> LDS direct DMA, 16B per lane. dest = wave-uniform base + lane*16.
static __device__ __forceinline__ void gload_lds16(const void* g, void* l) {
  __builtin_amdgcn_global_load_lds(
      (const __attribute__((address_space(1))) unsigned int*)g,
      (__attribute__((address_space(3))) unsigned int*)l, 16, 0, 0);
}

// ---------------------------------------------------------------- k_cvt
__global__ void k_cvt(const float* __restrict__ in, unsigned short* __restrict__ out, int n4) {
  int i = blockIdx.x * blockDim.x + threadIdx.x;
  int stride = gridDim.x * blockDim.x;
  for (; i < n4; i += stride) {
    float4 v = ((const float4*)in)[i];
    ushort4 o = make_ushort4(f32_to_bf16(v.x), f32_to_bf16(v.y),
                             f32_to_bf16(v.z), f32_to_bf16(v.w));
    ((ushort4*)out)[i] = o;
  }
}

// ------------------------------------------- transpose + convert weights
// in: K x N f32 (row-major), out: N x K bf16 (row-major) == B^T
__global__ void k_transpose_cvt(const float* __restrict__ in, unsigned short* __restrict__ out,
                                int K, int N) {
  __shared__ float t[32][33];
  const int n0 = blockIdx.x * 32, k0 = blockIdx.y * 32;
  const int tx = threadIdx.x & 31, ty = threadIdx.x >> 5;  // 32 x 8
#pragma unroll
  for (int rr = 0; rr < 32; rr += 8)
    t[ty + rr][tx] = in[(size_t)(k0 + ty + rr) * N + n0 + tx];
  __syncthreads();
#pragma unroll
  for (int rr = 0; rr < 32; rr += 8)
    out[(size_t)(n0 + ty + rr) * K + k0 + tx] = f32_to_bf16(t[tx][ty + rr]);
}

// ----------------------------------------- fused bias+mask table (padded)
__global__ __launch_bounds__(256) void k_bm(const float* __restrict__ mask,
                                            const float* __restrict__ rel,
                                            float* __restrict__ bmt) {
  const int idx = blockIdx.x * 256 + threadIdx.x;   // w<<16 | h<<12 | i<<6 | j
  const int j = idx & 63, i = (idx >> 6) & 63, h = (idx >> 12) & 15, w = idx >> 16;
  float v = -1e30f;
  if (i < NWIN && j < NWIN) {
    const int rpi = ((j / 7) - (i / 7) + 6) * 13;
    v = mask[w * (NWIN * NWIN) + i * NWIN + j] + rel[rpi * NH + h];
  }
  bmt[idx] = v;
}

#define WAITB(N)                                              \
  do {                                                        \
    asm volatile("s_waitcnt vmcnt(" #N ")" ::: "memory");     \
    __builtin_amdgcn_sched_barrier(0);                        \
    __builtin_amdgcn_s_barrier();                             \
    __builtin_amdgcn_sched_barrier(0);                        \
  } while (0)

// ------------------------------------------------------------------ GEMM
// EXACT r5/r12 4-phase 256x256 K-loop (schedule-fragile; never touched).
// OUT_MODE: 0 = f32 row-major, 1 = bf16 row-major,
//           2 = bf16 qkv-blocked [b][h][{q,k,v}][49][32] (attn-friendly).
template <int OUT_MODE>
static __device__ __forceinline__ void gemm256_body(const unsigned short* __restrict__ A,
                                                    const unsigned short* __restrict__ BT,
                                                    const float* __restrict__ bias,
                                                    void* __restrict__ Cout,
                                                    int M, int N, int K,
                                                    unsigned short* lds0) {
  unsigned short (*lds)[2][16384] = (unsigned short (*)[2][16384])lds0;
  const int tid = threadIdx.x;
  const int lane = tid & 63, wave = tid >> 6;
  const int wr = wave >> 2, wc = wave & 3;      // 2 x 4 wave grid
  const int lr = lane & 15, lg = lane >> 4;

  // bijective XCD swizzle (gridDim.x % 8 == 0 for all call sites)
  const int nwg = gridDim.x, q8 = nwg >> 3;
  const int wg = (blockIdx.x & 7) * q8 + (blockIdx.x >> 3);
  const int gx = N >> 8;
  const int bx = wg % gx, by = wg / gx;
  const int m0 = by << 8, n0 = bx << 8;

  const int srow = lane & 15;
  const int scol = (lane >> 4) * 8;
  const int sRG = wave >> 1;
  const int scg = wave & 1;

  const f32x4 fz = {0.f, 0.f, 0.f, 0.f};
  f32x4 acc[8][4];
#pragma unroll
  for (int i = 0; i < 8; ++i)
#pragma unroll
    for (int j = 0; j < 4; ++j) acc[i][j] = fz;

  const int NT = K >> 6;

  auto stageU = [&](const unsigned short* G, int gbase, int op, int t, int u) {
    const int RG = 4 * u + sRG;  // row-group 0..15
    gload_lds16(G + (size_t)(gbase + RG * 16 + srow) * K + (t << 6) + scg * 32 + scol,
                &lds[t & 1][op][(RG >> 3) * 8192 + (((RG & 7) << 1) + scg) * 512]);
  };

  const int roff = lg * 128 + lr * 8;

  bf16x8 af[4][2];
  bf16x8 bf[2][2];
  bf16x8 bg[2][2];

#define LDA(h, mh)                                                              \
  do {                                                                          \
    const unsigned short* la = &lds[(h) & 1][0][wr * 8192];                     \
    _Pragma("unroll") for (int m = 0; m < 4; ++m)                               \
    _Pragma("unroll") for (int ks = 0; ks < 2; ++ks)                            \
        af[m][ks] = *(const bf16x8*)(la + ((((mh)*4 + m) * 2 + ks) * 512) + roff); \
  } while (0)

#define LDB(h, nh, DST)                                                         \
  do {                                                                          \
    const unsigned short* lb = &lds[(h) & 1][1][(wc >> 1) * 8192];              \
    _Pragma("unroll") for (int n = 0; n < 2; ++n)                               \
    _Pragma("unroll") for (int ks = 0; ks < 2; ++ks)                            \
        DST[n][ks] = *(const bf16x8*)(lb + ((((wc & 1) * 4 + (nh)*2 + n) * 2 + ks) * 512) + roff); \
  } while (0)

#define MFMA16(mh, nh, B)                                                       \
  do {                                                                          \
    __builtin_amdgcn_s_setprio(1);                                              \
    _Pragma("unroll") for (int m = 0; m < 4; ++m)                               \
    _Pragma("unroll") for (int n = 0; n < 2; ++n)                               \
    _Pragma("unroll") for (int ks = 0; ks < 2; ++ks)                            \
        acc[(mh)*4 + m][(nh)*2 + n] = __builtin_amdgcn_mfma_f32_16x16x32_bf16(  \
            af[m][ks], B[n][ks], acc[(mh)*4 + m][(nh)*2 + n], 0, 0, 0);         \
    __builtin_amdgcn_s_setprio(0);                                              \
  } while (0)

  // prologue: tile 0, unit order B0 B1 B2 B3 A0 A2 A1 A3 (8 loads/lane)
  stageU(BT, n0, 1, 0, 0); stageU(BT, n0, 1, 0, 1);
  stageU(BT, n0, 1, 0, 2); stageU(BT, n0, 1, 0, 3);
  stageU(A,  m0, 0, 0, 0); stageU(A,  m0, 0, 0, 2);
  stageU(A,  m0, 0, 0, 1); stageU(A,  m0, 0, 0, 3);

  for (int h = 0; h < NT - 1; ++h) {
    const int t1 = h + 1;
    WAITB(2);
    stageU(BT, n0, 1, t1, 0); stageU(BT, n0, 1, t1, 1);
    LDA(h, 0);
    LDB(h, 0, bf);
    MFMA16(0, 0, bf);
    stageU(BT, n0, 1, t1, 2); stageU(BT, n0, 1, t1, 3);
    LDB(h, 1, bg);
    MFMA16(0, 1, bg);
    WAITB(4);
    stageU(A, m0, 0, t1, 0); stageU(A, m0, 0, t1, 2);
    LDA(h, 1);
    MFMA16(1, 1, bg);
    stageU(A, m0, 0, t1, 1); stageU(A, m0, 0, t1, 3);
    LDB(h, 0, bf);
    MFMA16(1, 0, bf);
  }
  {  // last tile, peeled
    const int h = NT - 1;
    WAITB(2);
    LDA(h, 0);
    LDB(h, 0, bf);
    MFMA16(0, 0, bf);
    LDB(h, 1, bg);
    MFMA16(0, 1, bg);
    WAITB(0);
    LDA(h, 1);
    MFMA16(1, 1, bg);
    LDB(h, 0, bf);
    MFMA16(1, 0, bf);
  }
#undef LDA
#undef LDB
#undef MFMA16

  float bv[4];
#pragma unroll
  for (int nj = 0; nj < 4; ++nj) bv[nj] = bias[n0 + wc * 64 + nj * 16 + lr];
#pragma unroll
  for (int mi = 0; mi < 8; ++mi)
#pragma unroll
    for (int nj = 0; nj < 4; ++nj)
#pragma unroll
      for (int r = 0; r < 4; ++r) {
        const int row = m0 + wr * 128 + mi * 16 + 4 * lg + r;
        const int col = n0 + wc * 64 + nj * 16 + lr;
        const float v = acc[mi][nj][r] + bv[nj];
        if (OUT_MODE == 2) {
          // qkv-blocked: row -> (b = row/49, i = row%49); col -> (which, h, d)
          const unsigned int b = (unsigned int)row / 49u;
          const unsigned int i = (unsigned int)row - b * 49u;
          const int which = col >> 9, hh = (col >> 5) & 15, d = col & 31;
          ((unsigned short*)Cout)[(((size_t)b * NH + hh) * 147 + which * 49 + i) * 32 + d] =
              f32_to_bf16(v);
        } else if (OUT_MODE == 1) {
          ((unsigned short*)Cout)[(size_t)row * N + col] = f32_to_bf16(v);
        } else {
          ((float*)Cout)[(size_t)row * N + col] = v;
        }
      }
}

__global__ __launch_bounds__(512, 2) void k_gemm_qkv(const unsigned short* __restrict__ A,
                                                     const unsigned short* __restrict__ BT,
                                                     const float* __restrict__ bias,
                                                     void* __restrict__ Cout,
                                                     int M, int N, int K) {
  __shared__ __align__(16) unsigned short lds[2][2][16384];  // 128 KB
  gemm256_body<2>(A, BT, bias, Cout, M, N, K, &lds[0][0][0]);
}

__global__ __launch_bounds__(512, 2) void k_gemm_proj(const unsigned short* __restrict__ A,
                                                      const unsigned short* __restrict__ BT,
                                                      const float* __restrict__ bias,
                                                      void* __restrict__ Cout,
                                                      int M, int N, int K) {
  __shared__ __align__(16) unsigned short lds[2][2][16384];  // 128 KB
  gemm256_body<0>(A, BT, bias, Cout, M, N, K, &lds[0][0][0]);
}

// ------------------------------------------------------------- attention
// r14-proven best (attn ~117 us): block = (w, h, tg), 4 waves handle
// b = w + 64*(4*tg + wave) sharing one LDS-staged (w,h) bias+mask table;
// XCD swizzle clusters w so per-XCD table set (2 MB) is L2-resident.
// qkv in blocked layout [b][h][{q,k,v}][49][32] (r13).
__global__ __launch_bounds__(256) void k_attn(const unsigned short* __restrict__ qkv,
                                              const float* __restrict__ bmt,
                                              unsigned short* __restrict__ aout) {
  const int wave = threadIdx.x >> 6, lane = threadIdx.x & 63;
  const int lr = lane & 15, lg = lane >> 4;

  // bijective XCD swizzle over 8192 blocks (q8 = 1024): XCD x gets
  // s in [1024x, 1024x+1024) -> w in [8x, 8x+8).
  const int s = (blockIdx.x & 7) * 1024 + (blockIdx.x >> 3);
  const int w = s >> 7, h = (s >> 3) & 15, tg = s & 7;
  const int b = w + 64 * (tg * 4 + wave);

  __shared__ float bml[64 * 66];                        // 16.9 KB shared table
  __shared__ __align__(16) unsigned short Pl[4][2048];  // per-wave P
  __shared__ __align__(16) unsigned short Vt[4][2112];  // per-wave V^T
  unsigned short* pl = Pl[wave];
  unsigned short* vt = Vt[wave];

  // ---- stage bmt(w,h) -> LDS (coalesced 16 KB read; issued first) ----
  const float* tbl = bmt + ((size_t)(w * NH + h) << 12);
#pragma unroll
  for (int it = 0; it < 4; ++it) {
    const int c = threadIdx.x + 256 * it;   // 16B chunk 0..1023
    const int row = c >> 4, col4 = c & 15;
    const f32x4 t4 = *(const f32x4*)(tbl + row * 64 + col4 * 4);
    float* dst = &bml[row * 66 + col4 * 4];
    dst[0] = t4[0]; dst[1] = t4[1]; dst[2] = t4[2]; dst[3] = t4[3];
  }

  const unsigned short* qp = qkv + ((size_t)(b * NH + h) * 147) * 32;
  const unsigned short* kp = qp + 49 * 32;
  const unsigned short* vp = qp + 2 * 49 * 32;

  bf16x8 kf[4], qf[4];
#pragma unroll
  for (int t = 0; t < 4; ++t) {
    kf[t] = *(const bf16x8*)(kp + (t * 16 + lr) * 32 + lg * 8);
    qf[t] = *(const bf16x8*)(qp + (t * 16 + lr) * 32 + lg * 8);
  }

  const u32x4 zv = {0u, 0u, 0u, 0u};
#pragma unroll
  for (int c0 = 0; c0 < 4; ++c0) {
    const int c = c0 * 64 + lane;
    const int key = c >> 2, d0 = (c & 3) << 3;
    union { u32x4 v; unsigned short ss[8]; } tmp;
    tmp.v = (key < NWIN) ? *(const u32x4*)(vp + key * 32 + d0) : zv;
#pragma unroll
    for (int jj = 0; jj < 8; ++jj) vt[(d0 + jj) * 66 + key] = tmp.ss[jj];
  }

  const f32x4 fz = {0.f, 0.f, 0.f, 0.f};
  f32x4 s4[4][4];
#pragma unroll
  for (int mi = 0; mi < 4; ++mi)
#pragma unroll
    for (int ni = 0; ni < 4; ++ni) s4[mi][ni] = fz;
#pragma unroll
  for (int mi = 0; mi < 4; ++mi)
#pragma unroll
    for (int ni = 0; ni < 4; ++ni)
      s4[mi][ni] = __builtin_amdgcn_mfma_f32_16x16x32_bf16(kf[mi], qf[ni], s4[mi][ni], 0, 0, 0);

  union VU { unsigned int u[4]; bf16x8 v; };
  VU vfr[2][2];
#pragma unroll
  for (int nj = 0; nj < 2; ++nj)
#pragma unroll
    for (int ks = 0; ks < 2; ++ks) {
      const int base = ((16 * nj + lr) * 66 + 32 * ks + 8 * lg) >> 1;
#pragma unroll
      for (int u = 0; u < 4; ++u) vfr[nj][ks].u[u] = ((const unsigned int*)vt)[base + u];
    }

  __syncthreads();  // bml staged (QK^T hid the latency)

  const float scale = 0.1767766952966369f;

  f32x4 o[4][2];
#pragma unroll
  for (int qi = 0; qi < 4; ++qi)
#pragma unroll
    for (int nj = 0; nj < 2; ++nj) o[qi][nj] = fz;

#pragma unroll
  for (int ni = 0; ni < 4; ++ni) {
    float v[16];
    float mx = -3e38f;
    const float* brow = &bml[(16 * ni + lr) * 66];
#pragma unroll
    for (int mi = 0; mi < 4; ++mi) {
#pragma unroll
      for (int r = 0; r < 4; ++r) {
        v[mi * 4 + r] = fmaf(s4[mi][ni][r], scale, brow[16 * mi + 4 * lg + r]);
        mx = fmaxf(mx, v[mi * 4 + r]);
      }
    }
    mx = fmaxf(mx, __shfl_xor(mx, 16));
    mx = fmaxf(mx, __shfl_xor(mx, 32));
    float sum = 0.f;
#pragma unroll
    for (int t = 0; t < 16; ++t) {
      v[t] = __expf(v[t] - mx);
      sum += v[t];
    }
    sum += __shfl_xor(sum, 16);
    sum += __shfl_xor(sum, 32);
    const float inv = __builtin_amdgcn_rcpf(sum);

    const int ip = 16 * (ni & 1) + lr;
#pragma unroll
    for (int mi = 0; mi < 4; ++mi) {
      const unsigned int lo = (unsigned int)f32_to_bf16(v[mi * 4 + 0] * inv) |
                              ((unsigned int)f32_to_bf16(v[mi * 4 + 1] * inv) << 16);
      const unsigned int hi = (unsigned int)f32_to_bf16(v[mi * 4 + 2] * inv) |
                              ((unsigned int)f32_to_bf16(v[mi * 4 + 3] * inv) << 16);
      const int byteoff = 32 * mi + 8 * lg;
      const int sw = byteoff ^ ((ip & 7) << 4);
      uint2 w2; w2.x = lo; w2.y = hi;
      *(uint2*)((char*)pl + ip * 128 + sw) = w2;
    }

    if (ni & 1) {
      asm volatile("s_waitcnt lgkmcnt(0)" ::: "memory");
      __builtin_amdgcn_sched_barrier(0);
      const int half = ni >> 1;
#pragma unroll
      for (int q2 = 0; q2 < 2; ++q2) {
        const int qi = half * 2 + q2;
        const int ipr = 16 * q2 + lr;
#pragma unroll
        for (int ks = 0; ks < 2; ++ks) {
          const int bo = 64 * ks + 16 * lg;
          const int swr = bo ^ ((ipr & 7) << 4);
          const bf16x8 pa = *(const bf16x8*)((const char*)pl + ipr * 128 + swr);
#pragma unroll
          for (int nj = 0; nj < 2; ++nj)
            o[qi][nj] = __builtin_amdgcn_mfma_f32_16x16x32_bf16(pa, vfr[nj][ks].v, o[qi][nj], 0, 0, 0);
        }
      }
    }
  }

  const size_t orow = (size_t)b * NWIN;
#pragma unroll
  for (int qi = 0; qi < 4; ++qi)
#pragma unroll
    for (int r = 0; r < 4; ++r) {
      const int i = 16 * qi + 4 * lg + r;
      if (i < NWIN) {
#pragma unroll
        for (int nj = 0; nj < 2; ++nj)
          aout[(orow + i) * C_DIM + h * HD + 16 * nj + lr] = f32_to_bf16(o[qi][nj][r]);
      }
    }
}

// ---------------------------------------------------------------- launch
static const size_t SZ_QKV = (size_t)M_ROWS * QKV_N * 2;   // 308 MB (blocked layout)
static const size_t SZ_XB  = (size_t)M_ROWS * C_DIM * 2;
static const size_t SZ_WQ  = (size_t)QKV_N * C_DIM * 2;
static const size_t OFF_QKV = 0;
static const size_t OFF_XB  = OFF_QKV + SZ_QKV;   // x_bf16, later attn_out
static const size_t OFF_WQ  = OFF_XB + SZ_XB;
static const size_t OFF_WP  = OFF_WQ + SZ_WQ;

extern "C" void kernel_launch(void* const* d_in, const int* in_sizes, int n_in,
                              void* d_out, int out_size, void* d_ws, size_t ws_size,
                              hipStream_t stream) {
  const float* x      = (const float*)d_in[0];
  const float* mask   = (const float*)d_in[1];
  const float* qkv_w  = (const float*)d_in[2];
  const float* qkv_b  = (const float*)d_in[3];
  const float* proj_w = (const float*)d_in[4];
  const float* proj_b = (const float*)d_in[5];
  const float* rel    = (const float*)d_in[6];
  float* out = (float*)d_out;

  char* ws = (char*)d_ws;
  unsigned short* qkvb = (unsigned short*)(ws + OFF_QKV);
  unsigned short* xb   = (unsigned short*)(ws + OFF_XB);
  unsigned short* wqT  = (unsigned short*)(ws + OFF_WQ);
  unsigned short* wpT  = (unsigned short*)(ws + OFF_WP);
  // bmt (16.78 MB) in d_out scratch: fully consumed by k_attn before final GEMM.
  float* bmt = (float*)d_out;

  k_cvt<<<2048, 256, 0, stream>>>(x, xb, M_ROWS * C_DIM / 4);
  k_transpose_cvt<<<dim3(QKV_N / 32, C_DIM / 32), 256, 0, stream>>>(qkv_w, wqT, C_DIM, QKV_N);
  k_transpose_cvt<<<dim3(C_DIM / 32, C_DIM / 32), 256, 0, stream>>>(proj_w, wpT, C_DIM, C_DIM);
  k_bm<<<(NMASK * NH * 64 * 64) / 256, 256, 0, stream>>>(mask, rel, bmt);

  // qkv = x @ qkv_w + qkv_b  (bf16, blocked layout), grid 6*392 = 2352 (%8==0)
  k_gemm_qkv<<<(QKV_N / 256) * (M_ROWS / 256), 512, 0, stream>>>(
      xb, wqT, qkv_b, qkvb, M_ROWS, QKV_N, C_DIM);

  // attention -> attn_out (reuses xb region), 8192 blocks (%8==0)
  k_attn<<<NMASK * NH * 8, 256, 0, stream>>>(qkvb, bmt, xb);

  // out = attn_out @ proj_w + proj_b  (f32 out), grid 2*392 = 784 (%8==0)
  k_gemm_proj<<<(C_DIM / 256) * (M_ROWS / 256), 512, 0, stream>>>(
      xb, wpT, proj_b, out, M_ROWS, C_DIM, C_DIM);
}

// Round 21
// 491.775 us; speedup vs baseline: 1.0329x; 1.0066x over previous
//
#include <hip/hip_runtime.h>
#include <hip/hip_bf16.h>
#include <stdint.h>

// Problem constants (match setup_inputs)
#define M_ROWS 100352   // 2048 * 49
#define C_DIM  512
#define QKV_N  1536
#define NH     16
#define HD     32
#define NWIN   49       // window tokens (7*7)
#define NMASK  64

typedef __attribute__((ext_vector_type(4))) float        f32x4;
typedef __attribute__((ext_vector_type(8))) short        bf16x8;
typedef __attribute__((ext_vector_type(4))) unsigned int u32x4;

static __device__ __forceinline__ unsigned short f32_to_bf16(float f) {
  union { float f; unsigned int u; } v; v.f = f;
  unsigned int u = v.u;
  return (unsigned short)((u + 0x7FFFu + ((u >> 16) & 1u)) >> 16);  // RNE
}

// global -> LDS direct DMA, 16B per lane. dest = wave-uniform base + lane*16.
static __device__ __forceinline__ void gload_lds16(const void* g, void* l) {
  __builtin_amdgcn_global_load_lds(
      (const __attribute__((address_space(1))) unsigned int*)g,
      (__attribute__((address_space(3))) unsigned int*)l, 16, 0, 0);
}

// ---------------------------------------------------------------- k_cvt
__global__ void k_cvt(const float* __restrict__ in, unsigned short* __restrict__ out, int n4) {
  int i = blockIdx.x * blockDim.x + threadIdx.x;
  int stride = gridDim.x * blockDim.x;
  for (; i < n4; i += stride) {
    float4 v = ((const float4*)in)[i];
    ushort4 o = make_ushort4(f32_to_bf16(v.x), f32_to_bf16(v.y),
                             f32_to_bf16(v.z), f32_to_bf16(v.w));
    ((ushort4*)out)[i] = o;
  }
}

// ------------------------------------------- transpose + convert weights
// in: K x N f32 (row-major), out: N x K bf16 (row-major) == B^T
__global__ void k_transpose_cvt(const float* __restrict__ in, unsigned short* __restrict__ out,
                                int K, int N) {
  __shared__ float t[32][33];
  const int n0 = blockIdx.x * 32, k0 = blockIdx.y * 32;
  const int tx = threadIdx.x & 31, ty = threadIdx.x >> 5;  // 32 x 8
#pragma unroll
  for (int rr = 0; rr < 32; rr += 8)
    t[ty + rr][tx] = in[(size_t)(k0 + ty + rr) * N + n0 + tx];
  __syncthreads();
#pragma unroll
  for (int rr = 0; rr < 32; rr += 8)
    out[(size_t)(n0 + ty + rr) * K + k0 + tx] = f32_to_bf16(t[tx][ty + rr]);
}

// ----------------------------------------- fused bias+mask table (padded)
__global__ __launch_bounds__(256) void k_bm(const float* __restrict__ mask,
                                            const float* __restrict__ rel,
                                            float* __restrict__ bmt) {
  const int idx = blockIdx.x * 256 + threadIdx.x;   // w<<16 | h<<12 | i<<6 | j
  const int j = idx & 63, i = (idx >> 6) & 63, h = (idx >> 12) & 15, w = idx >> 16;
  float v = -1e30f;
  if (i < NWIN && j < NWIN) {
    const int rpi = ((j / 7) - (i / 7) + 6) * 13;
    v = mask[w * (NWIN * NWIN) + i * NWIN + j] + rel[rpi * NH + h];
  }
  bmt[idx] = v;
}

#define WAITB(N)                                              \
  do {                                                        \
    asm volatile("s_waitcnt vmcnt(" #N ")" ::: "memory");     \
    __builtin_amdgcn_sched_barrier(0);                        \
    __builtin_amdgcn_s_barrier();                             \
    __builtin_amdgcn_sched_barrier(0);                        \
  } while (0)

// ------------------------------------------------------------------ GEMM
// EXACT r5/r12 4-phase 256x256 K-loop (schedule-fragile; never touched).
// OUT_MODE: 0 = f32 row-major, 1 = bf16 row-major,
//           2 = bf16 qkv-blocked [b][h][{q,k,v}][49][32] (attn-friendly).
template <int OUT_MODE>
static __device__ __forceinline__ void gemm256_body(const unsigned short* __restrict__ A,
                                                    const unsigned short* __restrict__ BT,
                                                    const float* __restrict__ bias,
                                                    void* __restrict__ Cout,
                                                    int M, int N, int K,
                                                    unsigned short* lds0) {
  unsigned short (*lds)[2][16384] = (unsigned short (*)[2][16384])lds0;
  const int tid = threadIdx.x;
  const int lane = tid & 63, wave = tid >> 6;
  const int wr = wave >> 2, wc = wave & 3;      // 2 x 4 wave grid
  const int lr = lane & 15, lg = lane >> 4;

  // bijective XCD swizzle (gridDim.x % 8 == 0 for all call sites)
  const int nwg = gridDim.x, q8 = nwg >> 3;
  const int wg = (blockIdx.x & 7) * q8 + (blockIdx.x >> 3);
  const int gx = N >> 8;
  const int bx = wg % gx, by = wg / gx;
  const int m0 = by << 8, n0 = bx << 8;

  const int srow = lane & 15;
  const int scol = (lane >> 4) * 8;
  const int sRG = wave >> 1;
  const int scg = wave & 1;

  const f32x4 fz = {0.f, 0.f, 0.f, 0.f};
  f32x4 acc[8][4];
#pragma unroll
  for (int i = 0; i < 8; ++i)
#pragma unroll
    for (int j = 0; j < 4; ++j) acc[i][j] = fz;

  const int NT = K >> 6;

  auto stageU = [&](const unsigned short* G, int gbase, int op, int t, int u) {
    const int RG = 4 * u + sRG;  // row-group 0..15
    gload_lds16(G + (size_t)(gbase + RG * 16 + srow) * K + (t << 6) + scg * 32 + scol,
                &lds[t & 1][op][(RG >> 3) * 8192 + (((RG & 7) << 1) + scg) * 512]);
  };

  const int roff = lg * 128 + lr * 8;

  bf16x8 af[4][2];
  bf16x8 bf[2][2];
  bf16x8 bg[2][2];

#define LDA(h, mh)                                                              \
  do {                                                                          \
    const unsigned short* la = &lds[(h) & 1][0][wr * 8192];                     \
    _Pragma("unroll") for (int m = 0; m < 4; ++m)                               \
    _Pragma("unroll") for (int ks = 0; ks < 2; ++ks)                            \
        af[m][ks] = *(const bf16x8*)(la + ((((mh)*4 + m) * 2 + ks) * 512) + roff); \
  } while (0)

#define LDB(h, nh, DST)                                                         \
  do {                                                                          \
    const unsigned short* lb = &lds[(h) & 1][1][(wc >> 1) * 8192];              \
    _Pragma("unroll") for (int n = 0; n < 2; ++n)                               \
    _Pragma("unroll") for (int ks = 0; ks < 2; ++ks)                            \
        DST[n][ks] = *(const bf16x8*)(lb + ((((wc & 1) * 4 + (nh)*2 + n) * 2 + ks) * 512) + roff); \
  } while (0)

#define MFMA16(mh, nh, B)                                                       \
  do {                                                                          \
    __builtin_amdgcn_s_setprio(1);                                              \
    _Pragma("unroll") for (int m = 0; m < 4; ++m)                               \
    _Pragma("unroll") for (int n = 0; n < 2; ++n)                               \
    _Pragma("unroll") for (int ks = 0; ks < 2; ++ks)                            \
        acc[(mh)*4 + m][(nh)*2 + n] = __builtin_amdgcn_mfma_f32_16x16x32_bf16(  \
            af[m][ks], B[n][ks], acc[(mh)*4 + m][(nh)*2 + n], 0, 0, 0);         \
    __builtin_amdgcn_s_setprio(0);                                              \
  } while (0)

  // prologue: tile 0, unit order B0 B1 B2 B3 A0 A2 A1 A3 (8 loads/lane)
  stageU(BT, n0, 1, 0, 0); stageU(BT, n0, 1, 0, 1);
  stageU(BT, n0, 1, 0, 2); stageU(BT, n0, 1, 0, 3);
  stageU(A,  m0, 0, 0, 0); stageU(A,  m0, 0, 0, 2);
  stageU(A,  m0, 0, 0, 1); stageU(A,  m0, 0, 0, 3);

  for (int h = 0; h < NT - 1; ++h) {
    const int t1 = h + 1;
    WAITB(2);
    stageU(BT, n0, 1, t1, 0); stageU(BT, n0, 1, t1, 1);
    LDA(h, 0);
    LDB(h, 0, bf);
    MFMA16(0, 0, bf);
    stageU(BT, n0, 1, t1, 2); stageU(BT, n0, 1, t1, 3);
    LDB(h, 1, bg);
    MFMA16(0, 1, bg);
    WAITB(4);
    stageU(A, m0, 0, t1, 0); stageU(A, m0, 0, t1, 2);
    LDA(h, 1);
    MFMA16(1, 1, bg);
    stageU(A, m0, 0, t1, 1); stageU(A, m0, 0, t1, 3);
    LDB(h, 0, bf);
    MFMA16(1, 0, bf);
  }
  {  // last tile, peeled
    const int h = NT - 1;
    WAITB(2);
    LDA(h, 0);
    LDB(h, 0, bf);
    MFMA16(0, 0, bf);
    LDB(h, 1, bg);
    MFMA16(0, 1, bg);
    WAITB(0);
    LDA(h, 1);
    MFMA16(1, 1, bg);
    LDB(h, 0, bf);
    MFMA16(1, 0, bf);
  }
#undef LDA
#undef LDB
#undef MFMA16

  float bv[4];
#pragma unroll
  for (int nj = 0; nj < 4; ++nj) bv[nj] = bias[n0 + wc * 64 + nj * 16 + lr];
#pragma unroll
  for (int mi = 0; mi < 8; ++mi)
#pragma unroll
    for (int nj = 0; nj < 4; ++nj)
#pragma unroll
      for (int r = 0; r < 4; ++r) {
        const int row = m0 + wr * 128 + mi * 16 + 4 * lg + r;
        const int col = n0 + wc * 64 + nj * 16 + lr;
        const float v = acc[mi][nj][r] + bv[nj];
        if (OUT_MODE == 2) {
          // qkv-blocked: row -> (b = row/49, i = row%49); col -> (which, h, d)
          const unsigned int b = (unsigned int)row / 49u;
          const unsigned int i = (unsigned int)row - b * 49u;
          const int which = col >> 9, hh = (col >> 5) & 15, d = col & 31;
          ((unsigned short*)Cout)[(((size_t)b * NH + hh) * 147 + which * 49 + i) * 32 + d] =
              f32_to_bf16(v);
        } else if (OUT_MODE == 1) {
          ((unsigned short*)Cout)[(size_t)row * N + col] = f32_to_bf16(v);
        } else {
          ((float*)Cout)[(size_t)row * N + col] = v;
        }
      }
}

__global__ __launch_bounds__(512, 2) void k_gemm_qkv(const unsigned short* __restrict__ A,
                                                     const unsigned short* __restrict__ BT,
                                                     const float* __restrict__ bias,
                                                     void* __restrict__ Cout,
                                                     int M, int N, int K) {
  __shared__ __align__(16) unsigned short lds[2][2][16384];  // 128 KB
  gemm256_body<2>(A, BT, bias, Cout, M, N, K, &lds[0][0][0]);
}

__global__ __launch_bounds__(512, 2) void k_gemm_proj(const unsigned short* __restrict__ A,
                                                      const unsigned short* __restrict__ BT,
                                                      const float* __restrict__ bias,
                                                      void* __restrict__ Cout,
                                                      int M, int N, int K) {
  __shared__ __align__(16) unsigned short lds[2][2][16384];  // 128 KB
  gemm256_body<0>(A, BT, bias, Cout, M, N, K, &lds[0][0][0]);
}

// ------------------------------------------------------------- attention
// r14-proven best (attn ~117 us): block = (w, h, tg), 4 waves handle
// b = w + 64*(4*tg + wave) sharing one LDS-staged (w,h) bias+mask table;
// XCD swizzle clusters w so per-XCD table set (2 MB) is L2-resident.
// qkv in blocked layout [b][h][{q,k,v}][49][32] (r13).
__global__ __launch_bounds__(256) void k_attn(const unsigned short* __restrict__ qkv,
                                              const float* __restrict__ bmt,
                                              unsigned short* __restrict__ aout) {
  const int wave = threadIdx.x >> 6, lane = threadIdx.x & 63;
  const int lr = lane & 15, lg = lane >> 4;

  // bijective XCD swizzle over 8192 blocks (q8 = 1024): XCD x gets
  // s in [1024x, 1024x+1024) -> w in [8x, 8x+8).
  const int s = (blockIdx.x & 7) * 1024 + (blockIdx.x >> 3);
  const int w = s >> 7, h = (s >> 3) & 15, tg = s & 7;
  const int b = w + 64 * (tg * 4 + wave);

  __shared__ float bml[64 * 66];                        // 16.9 KB shared table
  __shared__ __align__(16) unsigned short Pl[4][2048];  // per-wave P
  __shared__ __align__(16) unsigned short Vt[4][2112];  // per-wave V^T
  unsigned short* pl = Pl[wave];
  unsigned short* vt = Vt[wave];

  // ---- stage bmt(w,h) -> LDS (coalesced 16 KB read; issued first) ----
  const float* tbl = bmt + ((size_t)(w * NH + h) << 12);
#pragma unroll
  for (int it = 0; it < 4; ++it) {
    const int c = threadIdx.x + 256 * it;   // 16B chunk 0..1023
    const int row = c >> 4, col4 = c & 15;
    const f32x4 t4 = *(const f32x4*)(tbl + row * 64 + col4 * 4);
    float* dst = &bml[row * 66 + col4 * 4];
    dst[0] = t4[0]; dst[1] = t4[1]; dst[2] = t4[2]; dst[3] = t4[3];
  }

  const unsigned short* qp = qkv + ((size_t)(b * NH + h) * 147) * 32;
  const unsigned short* kp = qp + 49 * 32;
  const unsigned short* vp = qp + 2 * 49 * 32;

  bf16x8 kf[4], qf[4];
#pragma unroll
  for (int t = 0; t < 4; ++t) {
    kf[t] = *(const bf16x8*)(kp + (t * 16 + lr) * 32 + lg * 8);
    qf[t] = *(const bf16x8*)(qp + (t * 16 + lr) * 32 + lg * 8);
  }

  const u32x4 zv = {0u, 0u, 0u, 0u};
#pragma unroll
  for (int c0 = 0; c0 < 4; ++c0) {
    const int c = c0 * 64 + lane;
    const int key = c >> 2, d0 = (c & 3) << 3;
    union { u32x4 v; unsigned short ss[8]; } tmp;
    tmp.v = (key < NWIN) ? *(const u32x4*)(vp + key * 32 + d0) : zv;
#pragma unroll
    for (int jj = 0; jj < 8; ++jj) vt[(d0 + jj) * 66 + key] = tmp.ss[jj];
  }

  const f32x4 fz = {0.f, 0.f, 0.f, 0.f};
  f32x4 s4[4][4];
#pragma unroll
  for (int mi = 0; mi < 4; ++mi)
#pragma unroll
    for (int ni = 0; ni < 4; ++ni) s4[mi][ni] = fz;
#pragma unroll
  for (int mi = 0; mi < 4; ++mi)
#pragma unroll
    for (int ni = 0; ni < 4; ++ni)
      s4[mi][ni] = __builtin_amdgcn_mfma_f32_16x16x32_bf16(kf[mi], qf[ni], s4[mi][ni], 0, 0, 0);

  union VU { unsigned int u[4]; bf16x8 v; };
  VU vfr[2][2];
#pragma unroll
  for (int nj = 0; nj < 2; ++nj)
#pragma unroll
    for (int ks = 0; ks < 2; ++ks) {
      const int base = ((16 * nj + lr) * 66 + 32 * ks + 8 * lg) >> 1;
#pragma unroll
      for (int u = 0; u < 4; ++u) vfr[nj][ks].u[u] = ((const unsigned int*)vt)[base + u];
    }

  __syncthreads();  // bml staged (QK^T hid the latency)

  const float scale = 0.1767766952966369f;

  f32x4 o[4][2];
#pragma unroll
  for (int qi = 0; qi < 4; ++qi)
#pragma unroll
    for (int nj = 0; nj < 2; ++nj) o[qi][nj] = fz;

#pragma unroll
  for (int ni = 0; ni < 4; ++ni) {
    float v[16];
    float mx = -3e38f;
    const float* brow = &bml[(16 * ni + lr) * 66];
#pragma unroll
    for (int mi = 0; mi < 4; ++mi) {
#pragma unroll
      for (int r = 0; r < 4; ++r) {
        v[mi * 4 + r] = fmaf(s4[mi][ni][r], scale, brow[16 * mi + 4 * lg + r]);
        mx = fmaxf(mx, v[mi * 4 + r]);
      }
    }
    mx = fmaxf(mx, __shfl_xor(mx, 16));
    mx = fmaxf(mx, __shfl_xor(mx, 32));
    float sum = 0.f;
#pragma unroll
    for (int t = 0; t < 16; ++t) {
      v[t] = __expf(v[t] - mx);
      sum += v[t];
    }
    sum += __shfl_xor(sum, 16);
    sum += __shfl_xor(sum, 32);
    const float inv = __builtin_amdgcn_rcpf(sum);

    const int ip = 16 * (ni & 1) + lr;
#pragma unroll
    for (int mi = 0; mi < 4; ++mi) {
      const unsigned int lo = (unsigned int)f32_to_bf16(v[mi * 4 + 0] * inv) |
                              ((unsigned int)f32_to_bf16(v[mi * 4 + 1] * inv) << 16);
      const unsigned int hi = (unsigned int)f32_to_bf16(v[mi * 4 + 2] * inv) |
                              ((unsigned int)f32_to_bf16(v[mi * 4 + 3] * inv) << 16);
      const int byteoff = 32 * mi + 8 * lg;
      const int sw = byteoff ^ ((ip & 7) << 4);
      uint2 w2; w2.x = lo; w2.y = hi;
      *(uint2*)((char*)pl + ip * 128 + sw) = w2;
    }

    if (ni & 1) {
      asm volatile("s_waitcnt lgkmcnt(0)" ::: "memory");
      __builtin_amdgcn_sched_barrier(0);
      const int half = ni >> 1;
#pragma unroll
      for (int q2 = 0; q2 < 2; ++q2) {
        const int qi = half * 2 + q2;
        const int ipr = 16 * q2 + lr;
#pragma unroll
        for (int ks = 0; ks < 2; ++ks) {
          const int bo = 64 * ks + 16 * lg;
          const int swr = bo ^ ((ipr & 7) << 4);
          const bf16x8 pa = *(const bf16x8*)((const char*)pl + ipr * 128 + swr);
#pragma unroll
          for (int nj = 0; nj < 2; ++nj)
            o[qi][nj] = __builtin_amdgcn_mfma_f32_16x16x32_bf16(pa, vfr[nj][ks].v, o[qi][nj], 0, 0, 0);
        }
      }
    }
  }

  const size_t orow = (size_t)b * NWIN;
#pragma unroll
  for (int qi = 0; qi < 4; ++qi)
#pragma unroll
    for (int r = 0; r < 4; ++r) {
      const int i = 16 * qi + 4 * lg + r;
      if (i < NWIN) {
#pragma unroll
        for (int nj = 0; nj < 2; ++nj)
          aout[(orow + i) * C_DIM + h * HD + 16 * nj + lr] = f32_to_bf16(o[qi][nj][r]);
      }
    }
}

// ---------------------------------------------------------------- launch
static const size_t SZ_QKV = (size_t)M_ROWS * QKV_N * 2;   // 308 MB (blocked layout)
static const size_t SZ_XB  = (size_t)M_ROWS * C_DIM * 2;
static const size_t SZ_WQ  = (size_t)QKV_N * C_DIM * 2;
static const size_t OFF_QKV = 0;
static const size_t OFF_XB  = OFF_QKV + SZ_QKV;   // x_bf16, later attn_out
static const size_t OFF_WQ  = OFF_XB + SZ_XB;
static const size_t OFF_WP  = OFF_WQ + SZ_WQ;

extern "C" void kernel_launch(void* const* d_in, const int* in_sizes, int n_in,
                              void* d_out, int out_size, void* d_ws, size_t ws_size,
                              hipStream_t stream) {
  const float* x      = (const float*)d_in[0];
  const float* mask   = (const float*)d_in[1];
  const float* qkv_w  = (const float*)d_in[2];
  const float* qkv_b  = (const float*)d_in[3];
  const float* proj_w = (const float*)d_in[4];
  const float* proj_b = (const float*)d_in[5];
  const float* rel    = (const float*)d_in[6];
  float* out = (float*)d_out;

  char* ws = (char*)d_ws;
  unsigned short* qkvb = (unsigned short*)(ws + OFF_QKV);
  unsigned short* xb   = (unsigned short*)(ws + OFF_XB);
  unsigned short* wqT  = (unsigned short*)(ws + OFF_WQ);
  unsigned short* wpT  = (unsigned short*)(ws + OFF_WP);
  // bmt (16.78 MB) in d_out scratch: fully consumed by k_attn before final GEMM.
  float* bmt = (float*)d_out;

  k_cvt<<<2048, 256, 0, stream>>>(x, xb, M_ROWS * C_DIM / 4);
  k_transpose_cvt<<<dim3(QKV_N / 32, C_DIM / 32), 256, 0, stream>>>(qkv_w, wqT, C_DIM, QKV_N);
  k_transpose_cvt<<<dim3(C_DIM / 32, C_DIM / 32), 256, 0, stream>>>(proj_w, wpT, C_DIM, C_DIM);
  k_bm<<<(NMASK * NH * 64 * 64) / 256, 256, 0, stream>>>(mask, rel, bmt);

  // qkv = x @ qkv_w + qkv_b  (bf16, blocked layout), grid 6*392 = 2352 (%8==0)
  k_gemm_qkv<<<(QKV_N / 256) * (M_ROWS / 256), 512, 0, stream>>>(
      xb, wqT, qkv_b, qkvb, M_ROWS, QKV_N, C_DIM);

  // attention -> attn_out (reuses xb region), 8192 blocks (%8==0)
  k_attn<<<NMASK * NH * 8, 256, 0, stream>>>(qkvb, bmt, xb);

  // out = attn_out @ proj_w + proj_b  (f32 out), grid 2*392 = 784 (%8==0)
  k_gemm_proj<<<(C_DIM / 256) * (M_ROWS / 256), 512, 0, stream>>>(
      xb, wpT, proj_b, out, M_ROWS, C_DIM, C_DIM);
}